// Round 5
// baseline (93.389 us; speedup 1.0000x reference)
//
#include <hip/hip_runtime.h>
#include <hip/hip_bf16.h>
#include <math.h>

// MoBoAligner forward — closed-form O(B*I*J) reformulation.
//
//   val[b,i,j]   = soft_ok ? (dot/256 - log(-log(u)))/temp : -1000
//   S_geq[b,i,k] = LSE_{j>=k} val[b,i,j]                (reverse cum-LSE)
//   g_i[p] = alpha_i[p] - S_geq[i][p+1]  (empty if p==J-1 or !mel_mask[p])
//   C_i    = prefix cumLSE of g_i        (exact per-prefix max via (m,s) pairs)
//   alpha_{i+1}[j] = val[i][j-1] + C_i[j-2]    (masked j >= i+1)
//   w[i][q]  = exp(S_geq[i][q] + C_i[q-1]) + (J-q)*e^-10   ( = exp(delta) )
//   delta = log(w)  (fused into kernelB);  expanded = sum_i w*text (kernelC)
//
// kernelB: 4 waves / batch, 2 elems/lane, log2-domain (m,s) pairs, DPP wave
// scans + 64B LDS cross-wave exchange, zero logs on the DP chain.

#define B_ 4
#define I_ 64
#define J_ 512
#define D_ 256

#define NEGINF (-INFINITY)
#define SENT (-1.0e30f)   // finite "-inf" sentinel: keeps all arithmetic NaN-free
#define LOG2E 1.4426950408889634f

// ---------------- Threefry-2x32-20, key = (0, 42) --------------------------
__device__ __forceinline__ void tf2x32(unsigned int x0, unsigned int x1,
                                       unsigned int& y0, unsigned int& y1) {
  const unsigned int k0 = 0u, k1 = 42u;
  const unsigned int k2 = k0 ^ k1 ^ 0x1BD11BDAu;
  x0 += k0; x1 += k1;
#define TFR(r) { x0 += x1; x1 = (x1 << r) | (x1 >> (32 - r)); x1 ^= x0; }
  TFR(13) TFR(15) TFR(26) TFR(6)   x0 += k1; x1 += k2 + 1u;
  TFR(17) TFR(29) TFR(16) TFR(24)  x0 += k2; x1 += k0 + 2u;
  TFR(13) TFR(15) TFR(26) TFR(6)   x0 += k0; x1 += k1 + 3u;
  TFR(17) TFR(29) TFR(16) TFR(24)  x0 += k1; x1 += k2 + 4u;
  TFR(13) TFR(15) TFR(26) TFR(6)   x0 += k2; x1 += k0 + 5u;
#undef TFR
  y0 = x0; y1 = x1;
}

__device__ __forceinline__ unsigned int rand_bits(unsigned int n) {
  unsigned int y0, y1;
  tf2x32(0u, n, y0, y1);
  return y0 ^ y1;
}

// log(-log(u)) with u = jax.random.uniform(key(42), ..., 1e-20, 1.0)[n]
__device__ __forceinline__ float gumbel_term(unsigned int n) {
  unsigned int bits = rand_bits(n);
  float f = __uint_as_float((bits >> 9) | 0x3f800000u) - 1.0f;  // [0,1)
  float u = fmaxf(f + 1e-20f, 1e-20f);
  return logf(-logf(u));
}

// ---------------- streaming logsumexp pairs (kernelA, natural log) ---------
struct MS { float m; float s; };

__device__ __forceinline__ MS ms_comb(MS a, MS b) {
  if (b.m == NEGINF) return a;
  if (a.m == NEGINF) return b;
  MS r;
  if (a.m >= b.m) { r.m = a.m; r.s = a.s + b.s * __expf(b.m - a.m); }
  else            { r.m = b.m; r.s = b.s + a.s * __expf(a.m - b.m); }
  return r;
}
__device__ __forceinline__ MS ms_add(MS a, float x) {
  if (x == NEGINF) return a;
  if (a.m == NEGINF) { MS r; r.m = x; r.s = 1.0f; return r; }
  MS r;
  if (a.m >= x) { r.m = a.m; r.s = a.s + __expf(x - a.m); }
  else          { r.m = x;   r.s = 1.0f + a.s * __expf(a.m - x); }
  return r;
}
__device__ __forceinline__ float ms_val(MS a) {
  if (a.m == NEGINF) return NEGINF;
  return a.m + __logf(a.s);
}

__device__ __forceinline__ MS wave_incl_scan(MS v, int lane) {
  #pragma unroll
  for (int off = 1; off < 64; off <<= 1) {
    float mo = __shfl_up(v.m, off, 64);
    float so = __shfl_up(v.s, off, 64);
    if (lane >= off) { MS o; o.m = mo; o.s = so; v = ms_comb(o, v); }
  }
  return v;
}

// ---------------- branch-free (m,s) state in LOG2 domain (kernelB) ---------
// pair (m, s) represents value m + log2(s); (SENT, 0) == empty (-inf).
struct MS2 { float m; float s; };
__device__ __forceinline__ MS2 mk2(float m, float s) { MS2 r; r.m = m; r.s = s; return r; }

__device__ __forceinline__ MS2 comb2(MS2 a, MS2 b) {
  MS2 r;
  float d = a.m - b.m;
  r.m = fmaxf(a.m, b.m);
  float e = exp2f(-fabsf(d));           // single v_exp_f32 with -abs modifier
  float sbig   = (d >= 0.0f) ? a.s : b.s;
  float ssmall = (d >= 0.0f) ? b.s : a.s;
  r.s = fmaf(ssmall, e, sbig);
  return r;
}

template<int CTRL, int RM, int BM, bool BC>
__device__ __forceinline__ float dppf(float oldv, float src) {
  return __int_as_float(__builtin_amdgcn_update_dpp(
      __float_as_int(oldv), __float_as_int(src), CTRL, RM, BM, BC));
}

// move a pair through DPP; invalid lanes yield identity (SENT, 0)
template<int CTRL, int RM>
__device__ __forceinline__ MS2 dpp_ms(MS2 v) {
  MS2 r;
  r.m = dppf<CTRL, RM, 0xf, false>(SENT, v.m);
  r.s = dppf<CTRL, RM, 0xf, false>(0.0f, v.s);
  return r;
}

// inclusive (m,s) scan over 64 lanes: row_shr 1,2,4,8 + row_bcast 15,31
__device__ __forceinline__ MS2 wave_incl_scan_ms2(MS2 v) {
  v = comb2(dpp_ms<0x111, 0xf>(v), v);  // row_shr:1
  v = comb2(dpp_ms<0x112, 0xf>(v), v);  // row_shr:2
  v = comb2(dpp_ms<0x114, 0xf>(v), v);  // row_shr:4
  v = comb2(dpp_ms<0x118, 0xf>(v), v);  // row_shr:8
  v = comb2(dpp_ms<0x142, 0xa>(v), v);  // row_bcast:15 -> rows 1,3
  v = comb2(dpp_ms<0x143, 0xc>(v), v);  // row_bcast:31 -> rows 2,3
  return v;
}

// ---------------- mask helpers (bool-bytes vs int32 auto-detect) -----------
__device__ __forceinline__ bool mask_is_byte(const unsigned char* p) {
  const unsigned int* w = (const unsigned int*)p;
  unsigned int orbits = 0;
  #pragma unroll
  for (int k = 0; k < 16; k++) orbits |= w[k];
  return (orbits & 0xFFFFFF00u) != 0u;  // any high byte set -> byte layout
}
__device__ __forceinline__ int mask_get(const unsigned char* p, int idx, bool isbyte) {
  return isbyte ? (p[idx] != 0) : (((const int*)p)[idx] != 0);
}

// ============ Kernel A: val + S_geq per (b,i) row ==========================
__global__ __launch_bounds__(512) void kernelA(
    const float* __restrict__ text, const float* __restrict__ mel,
    const unsigned char* __restrict__ tmask, const unsigned char* __restrict__ mmask,
    const float* __restrict__ tratio,
    float* __restrict__ val, float* __restrict__ sgeq) {
  int bi = blockIdx.x;
  int b = bi >> 6, i = bi & 63;
  int tid = threadIdx.x;

  __shared__ float t_s[D_];
  __shared__ float v_s[J_];
  __shared__ int sh_ilen, sh_tok, sh_mbyte;

  if (tid == 0) {
    bool tbyte = mask_is_byte(tmask);
    int ilen = 0;
    for (int k = 0; k < I_; k++) ilen += mask_get(tmask, b * I_ + k, tbyte);
    sh_ilen = ilen;
    sh_tok = mask_get(tmask, b * I_ + i, tbyte);
    sh_mbyte = mask_is_byte(mmask) ? 1 : 0;
  }
  if (tid < D_) t_s[tid] = text[(size_t)(b * I_ + i) * D_ + tid];
  __syncthreads();

  int j = tid;  // 512 threads = one j each
  const float4* m4 = (const float4*)(mel + (size_t)(b * J_ + j) * D_);
  const float4* t4 = (const float4*)t_s;
  float4 acc; acc.x = acc.y = acc.z = acc.w = 0.0f;
  #pragma unroll 8
  for (int d4 = 0; d4 < D_ / 4; ++d4) {
    float4 a = m4[d4]; float4 t = t4[d4];
    acc.x += a.x * t.x; acc.y += a.y * t.y;
    acc.z += a.z * t.z; acc.w += a.w * t.w;
  }
  float dot = (acc.x + acc.y) + (acc.z + acc.w);

  float temp = 0.1f + 0.9f * tratio[0];
  float gum = gumbel_term((unsigned)((b * I_ + i) * J_ + j));
  float e = (dot * (1.0f / 256.0f) - gum) / temp;
  int mok = mask_get(mmask, b * J_ + j, sh_mbyte != 0);
  int hi = J_ - sh_ilen + i + 1;
  bool ok = (j >= i + 1) && (j <= hi) && mok && sh_tok;
  float v = ok ? e : -1000.0f;
  v_s[j] = v;
  val[(size_t)bi * J_ + j] = v;
  __syncthreads();

  // reverse cumulative LSE by wave 0: p = reversed index, lane l owns p=l*8+e
  if (tid < 64) {
    int l = tid;
    float xs[8];
    MS tot; tot.m = NEGINF; tot.s = 0.0f;
    #pragma unroll
    for (int e = 0; e < 8; e++) {
      int p = l * 8 + e;
      xs[e] = v_s[J_ - 1 - p];
      tot = ms_add(tot, xs[e]);
    }
    MS inc = wave_incl_scan(tot, l);
    MS ex; ex.m = __shfl_up(inc.m, 1, 64); ex.s = __shfl_up(inc.s, 1, 64);
    if (l == 0) { ex.m = NEGINF; ex.s = 0.0f; }
    MS run = ex;
    #pragma unroll
    for (int e = 0; e < 8; e++) {
      int p = l * 8 + e;
      run = ms_add(run, xs[e]);
      sgeq[(size_t)bi * J_ + (J_ - 1 - p)] = ms_val(run);
    }
  }
}

// ============ Kernel B: DP over i — 4 waves/batch, log2 domain =============
// 256 threads. wave w = tid>>6, lane l = tid&63, elems p = w*128 + l*2 + {0,1}.
// Per iter: in-lane comb + 6-step wave DPP scan + 64B LDS cross-wave exchange.
__global__ __launch_bounds__(256) void kernelB(
    const float* __restrict__ val, const float* __restrict__ sgeq,
    const unsigned char* __restrict__ mmask,
    float* __restrict__ wrow, float* __restrict__ delta) {
  const int b = blockIdx.x;
  const int tid = threadIdx.x;
  const int w = tid >> 6, l = tid & 63;
  const int p0 = (w << 7) + (l << 1);
  const int p1 = p0 + 1;

  __shared__ float4 xch[4];  // per-wave: (T.m, T.s, L126.m, L126.s)

  const bool mbyte = mask_is_byte(mmask);
  const bool gok0 = (p0 <= J_ - 2) && (mask_get(mmask, b * J_ + p0, mbyte) != 0);
  const bool gok1 = (p1 <= J_ - 2) && (mask_get(mmask, b * J_ + p1, mbyte) != 0);
  const float floor0 = (float)(J_ - p0) * 4.5399929762484854e-05f;
  const float floor1 = (float)(J_ - p1) * 4.5399929762484854e-05f;

  // alpha as log2-domain pair
  float Am0 = (p0 == 0) ? 0.0f : SENT, As0 = (p0 == 0) ? 1.0f : 0.0f;
  float Am1 = SENT, As1 = 0.0f;

  const float* sb = sgeq + (size_t)b * I_ * J_;
  const float* vb = val  + (size_t)b * I_ * J_;
  float* wb = wrow  + (size_t)b * I_ * J_;
  float* db = delta + (size_t)b * I_ * J_;

  const int ip1s = (p1 + 1 < J_) ? p1 + 1 : J_ - 1;  // clamped (dead when clamped)
  const int ip0m = (p0 > 0) ? p0 - 1 : 0;            // clamped (dead when clamped)

  // preload row 0
  float2 sg = *(const float2*)(sb + p0);
  float sgn = sb[ip1s];
  float va = vb[ip0m], vb0 = vb[p0];

  for (int i = 0; i < I_; i++) {
    // prefetch next row (clamped; redundant reload on last iter harmless)
    const float* srn = sb + (size_t)((i + 1 < I_) ? i + 1 : i) * J_;
    const float* vrn = vb + (size_t)((i + 1 < I_) ? i + 1 : i) * J_;
    float2 sgN = *(const float2*)(srn + p0);
    float sgnN = srn[ip1s];
    float vaN = vrn[ip0m], vb0N = vrn[p0];

    // convert to log2 domain
    float S20 = sg.x * LOG2E, S21 = sg.y * LOG2E, S2n = sgn * LOG2E;
    float v2a = va * LOG2E, v2b = vb0 * LOG2E;

    // g pairs: g[p] = alpha[p] - S[p+1]
    MS2 st0 = mk2(gok0 ? (Am0 - S21) : SENT, gok0 ? As0 : 0.0f);
    MS2 st1 = mk2(gok1 ? (Am1 - S2n) : SENT, gok1 ? As1 : 0.0f);

    MS2 p01 = comb2(st0, st1);                 // lane total (2 elems)
    MS2 incl = wave_incl_scan_ms2(p01);        // inclusive over lane-pairs
    MS2 le0 = dpp_ms<0x138, 0xf>(incl);        // wave_shr:1 -> local excl @ e0
    MS2 le1 = comb2(le0, st0);                 // local excl @ e1 (prefix thru e0)
    MS2 le1p = dpp_ms<0x138, 0xf>(le1);        // prev lane's le1 (lane0 -> ID)

    if (l == 63) xch[w] = make_float4(incl.m, incl.s, le1.m, le1.s);
    __syncthreads();
    float4 x0 = xch[0], x1 = xch[1], x2 = xch[2];
    __syncthreads();  // all reads done before next iter's writes

    // wave-uniform: prefix before wave w, before wave w-1, L126 of wave w-1
    MS2 pw, pwm1, L126p;
    if (w == 0)      { pw = mk2(SENT, 0.f); pwm1 = mk2(SENT, 0.f); L126p = mk2(SENT, 0.f); }
    else if (w == 1) { pw = mk2(x0.x, x0.y); pwm1 = mk2(SENT, 0.f); L126p = mk2(x0.z, x0.w); }
    else if (w == 2) { pw = comb2(mk2(x0.x, x0.y), mk2(x1.x, x1.y));
                       pwm1 = mk2(x0.x, x0.y); L126p = mk2(x1.z, x1.w); }
    else             { MS2 c01 = comb2(mk2(x0.x, x0.y), mk2(x1.x, x1.y));
                       pw = comb2(c01, mk2(x2.x, x2.y));
                       pwm1 = c01; L126p = mk2(x2.z, x2.w); }

    MS2 EX0 = comb2(pw, le0);      // global exclusive prefix at p0 (= C[p0-1])
    MS2 EX1 = comb2(pw, le1);      // at p1
    MS2 EXm1 = comb2(pw, le1p);    // at p0-1 (lanes >= 1)
    if (l == 0) EXm1 = comb2(pwm1, L126p);  // cross-wave (w=0: dead garbage)

    // w = exp2(S2 + EX.m)*EX.s + floor ; delta = log(w)
    float wo0 = fmaf(exp2f(S20 + EX0.m), EX0.s, floor0);
    float wo1 = fmaf(exp2f(S21 + EX1.m), EX1.s, floor1);
    float2* wst = (float2*)(wb + (size_t)i * J_ + p0);
    *wst = make_float2(wo0, wo1);
    float2* dst = (float2*)(db + (size_t)i * J_ + p0);
    *dst = make_float2(__logf(wo0), __logf(wo1));

    // alpha_{i+1}[p] = V[p-1] + C[p-2] -> pair (V2[p-1] + EX[p-1].m, EX[p-1].s)
    if (i < I_ - 1) {
      bool live0 = (p0 >= i + 1), live1 = (p1 >= i + 1);
      Am0 = live0 ? (v2a + EXm1.m) : SENT;  As0 = live0 ? EXm1.s : 0.0f;
      Am1 = live1 ? (v2b + EX0.m) : SENT;   As1 = live1 ? EX0.s : 0.0f;
    }
    sg = sgN; sgn = sgnN; va = vaN; vb0 = vb0N;
  }
}

// ============ Kernel C: expanded[b,j,d] = sum_i w * text ===================
__global__ __launch_bounds__(256) void kernelC(
    const float* __restrict__ wrow, const float* __restrict__ text,
    float* __restrict__ expanded) {
  int bj = blockIdx.x;
  int b = bj >> 9, j = bj & (J_ - 1);
  int d = threadIdx.x;
  __shared__ float w_s[I_];
  if (d < I_) w_s[d] = wrow[(size_t)(b * I_ + d) * J_ + j];
  __syncthreads();
  float acc = 0.0f;
  #pragma unroll 8
  for (int i = 0; i < I_; i++)
    acc += w_s[i] * text[(size_t)(b * I_ + i) * D_ + d];
  expanded[(size_t)(b * J_ + j) * D_ + d] = acc;
}

extern "C" void kernel_launch(void* const* d_in, const int* in_sizes, int n_in,
                              void* d_out, int out_size, void* d_ws, size_t ws_size,
                              hipStream_t stream) {
  (void)in_sizes; (void)n_in; (void)out_size; (void)ws_size;
  const float* text = (const float*)d_in[0];
  const float* mel  = (const float*)d_in[1];
  const unsigned char* tmask = (const unsigned char*)d_in[2];
  const unsigned char* mmask = (const unsigned char*)d_in[3];
  const float* tratio = (const float*)d_in[4];

  float* out = (float*)d_out;
  float* delta = out;                                  // B*I*J
  float* expanded = out + (size_t)B_ * I_ * J_;        // B*J*D
  float* val  = (float*)d_ws;                          // B*I*J
  float* sgeq = val + (size_t)B_ * I_ * J_;            // B*I*J
  float* wrow = sgeq + (size_t)B_ * I_ * J_;           // B*I*J

  kernelA<<<B_ * I_, 512, 0, stream>>>(text, mel, tmask, mmask, tratio, val, sgeq);
  kernelB<<<B_, 256, 0, stream>>>(val, sgeq, mmask, wrow, delta);
  kernelC<<<B_ * J_, 256, 0, stream>>>(wrow, text, expanded);
}

// Round 9
// 89.453 us; speedup vs baseline: 1.0440x; 1.0440x over previous
//
#include <hip/hip_runtime.h>
#include <hip/hip_bf16.h>
#include <math.h>

// MoBoAligner forward — closed-form O(B*I*J) reformulation.
//
//   val[b,i,j]   = soft_ok ? (dot/256 - log(-log(u)))/temp : -1000
//   S_geq[b,i,k] = LSE_{j>=k} val[b,i,j]                (reverse cum-LSE)
//   g_i[p] = alpha_i[p] - S_geq[i][p+1]  (-inf if p==J-1 or !mel_mask[p])
//   C_i    = prefix cumLSE of g_i
//   alpha_{i+1}[j] = val[i][j-1] + C_i[j-2]    (masked j >= i+1)
//   w[i][q]  = exp(S_geq[i][q] + C_i[q-1]) + (J-q)*e^-10   ( = exp(delta) )
//   delta = log(w);  expanded[b,j,d] = sum_i w * text  (kernelC)
//
// kernelB scale analysis (exact): true alpha <= 0 (LSE(alpha) non-increasing),
// S_geq is non-increasing and bimodal {normal >= -35, collapsed ~ -1443}.
// So gm = alpha - S[p+1] is bimodal: head (<= ~35) or spike (~alpha+1443).
// Collapsed-S positions form a SUFFIX -> per row, C[p] = LSE prefix splits:
//   head (before first spike): log2(plain prefix-sum of 2^gm)      [exact]
//   tail (spike seen):         T + log2(prefix-sum of 2^(gm-T))    [exact;
//        T = wave max; head cross-terms are 2^-1400 relative -> sub-ulp]
// Mid-scale gm in (60,500) only occurs for floor-dominated dead paths
// (alpha < -940): clamped to 2^60 for overflow safety, provably invisible.

#define B_ 4
#define I_ 64
#define J_ 512
#define D_ 256

#define NEGINF (-INFINITY)
#define LOG2E 1.4426950408889634f
#define SPIKE_THR 500.0f   // head gm <= ~35; spikes ~ +1443 (log2 units)
#define MIDCLAMP 60.0f     // overflow guard for dead-zone mid-scale gm

// ---------------- Threefry-2x32-20, key = (0, 42) --------------------------
__device__ __forceinline__ void tf2x32(unsigned int x0, unsigned int x1,
                                       unsigned int& y0, unsigned int& y1) {
  const unsigned int k0 = 0u, k1 = 42u;
  const unsigned int k2 = k0 ^ k1 ^ 0x1BD11BDAu;
  x0 += k0; x1 += k1;
#define TFR(r) { x0 += x1; x1 = (x1 << r) | (x1 >> (32 - r)); x1 ^= x0; }
  TFR(13) TFR(15) TFR(26) TFR(6)   x0 += k1; x1 += k2 + 1u;
  TFR(17) TFR(29) TFR(16) TFR(24)  x0 += k2; x1 += k0 + 2u;
  TFR(13) TFR(15) TFR(26) TFR(6)   x0 += k0; x1 += k1 + 3u;
  TFR(17) TFR(29) TFR(16) TFR(24)  x0 += k1; x1 += k2 + 4u;
  TFR(13) TFR(15) TFR(26) TFR(6)   x0 += k2; x1 += k0 + 5u;
#undef TFR
  y0 = x0; y1 = x1;
}

__device__ __forceinline__ unsigned int rand_bits(unsigned int n) {
  unsigned int y0, y1;
  tf2x32(0u, n, y0, y1);
  return y0 ^ y1;
}

// log(-log(u)) with u = jax.random.uniform(key(42), ..., 1e-20, 1.0)[n]
__device__ __forceinline__ float gumbel_term(unsigned int n) {
  unsigned int bits = rand_bits(n);
  float f = __uint_as_float((bits >> 9) | 0x3f800000u) - 1.0f;  // [0,1)
  float u = fmaxf(f + 1e-20f, 1e-20f);
  return logf(-logf(u));
}

// ---------------- streaming logsumexp pairs (kernelA, natural log) ---------
struct MS { float m; float s; };

__device__ __forceinline__ MS ms_comb(MS a, MS b) {
  if (b.m == NEGINF) return a;
  if (a.m == NEGINF) return b;
  MS r;
  if (a.m >= b.m) { r.m = a.m; r.s = a.s + b.s * __expf(b.m - a.m); }
  else            { r.m = b.m; r.s = b.s + a.s * __expf(a.m - b.m); }
  return r;
}
__device__ __forceinline__ MS ms_add(MS a, float x) {
  if (x == NEGINF) return a;
  if (a.m == NEGINF) { MS r; r.m = x; r.s = 1.0f; return r; }
  MS r;
  if (a.m >= x) { r.m = a.m; r.s = a.s + __expf(x - a.m); }
  else          { r.m = x;   r.s = 1.0f + a.s * __expf(a.m - x); }
  return r;
}
__device__ __forceinline__ float ms_val(MS a) {
  if (a.m == NEGINF) return NEGINF;
  return a.m + __logf(a.s);
}

__device__ __forceinline__ MS wave_incl_scan(MS v, int lane) {
  #pragma unroll
  for (int off = 1; off < 64; off <<= 1) {
    float mo = __shfl_up(v.m, off, 64);
    float so = __shfl_up(v.s, off, 64);
    if (lane >= off) { MS o; o.m = mo; o.s = so; v = ms_comb(o, v); }
  }
  return v;
}

// ---------------- DPP helpers (kernelB) ------------------------------------
template<int CTRL, int RM, int BM, bool BC>
__device__ __forceinline__ float dppf(float oldv, float src) {
  return __int_as_float(__builtin_amdgcn_update_dpp(
      __float_as_int(oldv), __float_as_int(src), CTRL, RM, BM, BC));
}

// inclusive float add-scan over 64 lanes (invalid sources contribute 0)
__device__ __forceinline__ float wave_incl_add_f(float x) {
  x += dppf<0x111, 0xf, 0xf, false>(0.0f, x);  // row_shr:1
  x += dppf<0x112, 0xf, 0xf, false>(0.0f, x);  // row_shr:2
  x += dppf<0x114, 0xf, 0xf, false>(0.0f, x);  // row_shr:4
  x += dppf<0x118, 0xf, 0xf, false>(0.0f, x);  // row_shr:8
  x += dppf<0x142, 0xa, 0xf, false>(0.0f, x);  // row_bcast:15 -> rows 1,3
  x += dppf<0x143, 0xc, 0xf, false>(0.0f, x);  // row_bcast:31 -> rows 2,3
  return x;
}
// inclusive float max-scan over 64 lanes (invalid sources give -inf: no-op)
__device__ __forceinline__ float wave_incl_max_f(float x) {
  x = fmaxf(x, dppf<0x111, 0xf, 0xf, false>(NEGINF, x));
  x = fmaxf(x, dppf<0x112, 0xf, 0xf, false>(NEGINF, x));
  x = fmaxf(x, dppf<0x114, 0xf, 0xf, false>(NEGINF, x));
  x = fmaxf(x, dppf<0x118, 0xf, 0xf, false>(NEGINF, x));
  x = fmaxf(x, dppf<0x142, 0xa, 0xf, false>(NEGINF, x));
  x = fmaxf(x, dppf<0x143, 0xc, 0xf, false>(NEGINF, x));
  return x;
}

// ---------------- mask helpers (bool-bytes vs int32 auto-detect) -----------
__device__ __forceinline__ bool mask_is_byte(const unsigned char* p) {
  const unsigned int* w = (const unsigned int*)p;
  unsigned int orbits = 0;
  #pragma unroll
  for (int k = 0; k < 16; k++) orbits |= w[k];
  return (orbits & 0xFFFFFF00u) != 0u;  // any high byte set -> byte layout
}
__device__ __forceinline__ int mask_get(const unsigned char* p, int idx, bool isbyte) {
  return isbyte ? (p[idx] != 0) : (((const int*)p)[idx] != 0);
}

// ============ Kernel A: val + S_geq per (b,i) row (stored in log2 domain) ==
__global__ __launch_bounds__(512) void kernelA(
    const float* __restrict__ text, const float* __restrict__ mel,
    const unsigned char* __restrict__ tmask, const unsigned char* __restrict__ mmask,
    const float* __restrict__ tratio,
    float* __restrict__ val2, float* __restrict__ sgeq2) {
  int bi = blockIdx.x;
  int b = bi >> 6, i = bi & 63;
  int tid = threadIdx.x;

  __shared__ float t_s[D_];
  __shared__ float v_s[J_];
  __shared__ int sh_ilen, sh_tok, sh_mbyte;

  if (tid == 0) {
    bool tbyte = mask_is_byte(tmask);
    int ilen = 0;
    for (int k = 0; k < I_; k++) ilen += mask_get(tmask, b * I_ + k, tbyte);
    sh_ilen = ilen;
    sh_tok = mask_get(tmask, b * I_ + i, tbyte);
    sh_mbyte = mask_is_byte(mmask) ? 1 : 0;
  }
  if (tid < D_) t_s[tid] = text[(size_t)(b * I_ + i) * D_ + tid];
  __syncthreads();

  int j = tid;  // 512 threads = one j each
  const float4* m4 = (const float4*)(mel + (size_t)(b * J_ + j) * D_);
  const float4* t4 = (const float4*)t_s;
  float4 acc; acc.x = acc.y = acc.z = acc.w = 0.0f;
  #pragma unroll 8
  for (int d4 = 0; d4 < D_ / 4; ++d4) {
    float4 a = m4[d4]; float4 t = t4[d4];
    acc.x += a.x * t.x; acc.y += a.y * t.y;
    acc.z += a.z * t.z; acc.w += a.w * t.w;
  }
  float dot = (acc.x + acc.y) + (acc.z + acc.w);

  float temp = 0.1f + 0.9f * tratio[0];
  float gum = gumbel_term((unsigned)((b * I_ + i) * J_ + j));
  float e = (dot * (1.0f / 256.0f) - gum) / temp;
  int mok = mask_get(mmask, b * J_ + j, sh_mbyte != 0);
  int hi = J_ - sh_ilen + i + 1;
  bool ok = (j >= i + 1) && (j <= hi) && mok && sh_tok;
  float v = ok ? e : -1000.0f;
  v_s[j] = v;                                   // natural log domain (internal)
  val2[(size_t)bi * J_ + j] = v * LOG2E;        // log2 domain for kernelB
  __syncthreads();

  // reverse cumulative LSE by wave 0: p = reversed index, lane l owns p=l*8+e
  if (tid < 64) {
    int l = tid;
    float xs[8];
    MS tot; tot.m = NEGINF; tot.s = 0.0f;
    #pragma unroll
    for (int e = 0; e < 8; e++) {
      int p = l * 8 + e;
      xs[e] = v_s[J_ - 1 - p];
      tot = ms_add(tot, xs[e]);
    }
    MS inc = wave_incl_scan(tot, l);
    MS ex; ex.m = __shfl_up(inc.m, 1, 64); ex.s = __shfl_up(inc.s, 1, 64);
    if (l == 0) { ex.m = NEGINF; ex.s = 0.0f; }
    MS run = ex;
    #pragma unroll
    for (int e = 0; e < 8; e++) {
      int p = l * 8 + e;
      run = ms_add(run, xs[e]);
      sgeq2[(size_t)bi * J_ + (J_ - 1 - p)] = ms_val(run) * LOG2E;
    }
  }
}

// ============ Kernel B: DP over i — 1 wave/batch, segmented 2-scale scan ===
// lane l owns p = l*8 + e. No LDS, no barriers. All values log2 domain.
// Two plain-add prefix scans per row: head at scale 2^0, tail (spikes) at
// scale 2^T (T = wave max via fmax scan + readlane). Alpha renormalized to
// a plain log2 number every iteration (no pair-drift, no inf*0).
__global__ __launch_bounds__(64) void kernelB(
    const float* __restrict__ val2, const float* __restrict__ sgeq2,
    const unsigned char* __restrict__ mmask,
    float* __restrict__ wrow, float* __restrict__ delta) {
  const int b = blockIdx.x;
  const int l = threadIdx.x;
  const int p0 = l << 3;

  const bool mbyte = mask_is_byte(mmask);
  float gokb[8], floorc[8], Am[8];
#pragma unroll
  for (int e = 0; e < 8; e++) {
    int p = p0 + e;
    bool ok = (p <= J_ - 2) && (mask_get(mmask, b * J_ + p, mbyte) != 0);
    gokb[e] = ok ? 0.0f : NEGINF;                           // additive mask
    floorc[e] = (float)(J_ - p) * 4.5399929762484854e-05f;  // (J-q)*e^-10
    Am[e] = (p == 0) ? 0.0f : NEGINF;
  }

  const float4* sb4 = (const float4*)(sgeq2 + (size_t)b * I_ * J_);
  const float4* vb4 = (const float4*)(val2  + (size_t)b * I_ * J_);
  float* wb = wrow  + (size_t)b * I_ * J_;
  float* db = delta + (size_t)b * I_ * J_;

  float4 Sq0 = sb4[l * 2], Sq1 = sb4[l * 2 + 1];
  float4 Vq0 = vb4[l * 2], Vq1 = vb4[l * 2 + 1];

  for (int i = 0; i < I_; i++) {
    // prefetch next row (clamped; redundant reload on last iter harmless)
    const int rn = (i + 1 < I_) ? i + 1 : i;
    const int ro = rn * (J_ / 4);
    float4 Sn0 = sb4[ro + l * 2], Sn1 = sb4[ro + l * 2 + 1];
    float4 Vn0 = vb4[ro + l * 2], Vn1 = vb4[ro + l * 2 + 1];

    float S[8] = {Sq0.x, Sq0.y, Sq0.z, Sq0.w, Sq1.x, Sq1.y, Sq1.z, Sq1.w};
    float V[8] = {Vq0.x, Vq0.y, Vq0.z, Vq0.w, Vq1.x, Vq1.y, Vq1.z, Vq1.w};

    // g[p] = alpha[p] - S[p+1] + mask; e=7 needs next lane's S[0]
    float nextS0 = dppf<0x130, 0xf, 0xf, false>(0.0f, S[0]);  // wave_shl:1
    float gm[8];
#pragma unroll
    for (int e = 0; e < 8; e++) {
      float sp1 = (e < 7) ? S[e + 1] : nextS0;
      gm[e] = (Am[e] - sp1) + gokb[e];   // -inf propagates, never NaN
    }

    // T = wave max of gm (only consumed at spike lanes, where it's finite)
    float m01 = fmaxf(gm[0], gm[1]), m23 = fmaxf(gm[2], gm[3]);
    float m45 = fmaxf(gm[4], gm[5]), m67 = fmaxf(gm[6], gm[7]);
    float lmax = fmaxf(fmaxf(m01, m23), fmaxf(m45, m67));
    float msc = wave_incl_max_f(lmax);
    const float T = __int_as_float(
        __builtin_amdgcn_readlane(__float_as_int(msc), 63));

    // two-scale exp terms: head at 2^0 (clamped), tail (spikes) at 2^T
    float h[8], t[8];
#pragma unroll
    for (int e = 0; e < 8; e++) {
      bool spk = gm[e] > SPIKE_THR;
      float arg = spk ? (gm[e] - T) : fminf(gm[e], MIDCLAMP);
      float x = __builtin_amdgcn_exp2f(arg);   // gm=-inf -> 0
      h[e] = spk ? 0.0f : x;
      t[e] = spk ? x : 0.0f;
    }

    // in-lane inclusive prefixes (two independent chains, ILP)
    float hp[8], tp[8];
    hp[0] = h[0]; tp[0] = t[0];
#pragma unroll
    for (int e = 1; e < 8; e++) { hp[e] = hp[e - 1] + h[e]; tp[e] = tp[e - 1] + t[e]; }

    // wave add-scans of lane totals; exclusive via wave_shr:1 (lane0 -> 0)
    float hincl = wave_incl_add_f(hp[7]);
    float tincl = wave_incl_add_f(tp[7]);
    float hx = dppf<0x138, 0xf, 0xf, false>(0.0f, hincl);
    float tx = dppf<0x138, 0xf, 0xf, false>(0.0f, tincl);

    // prefix sums through p-1, then C1[e] = C[p-1] (true log2 value)
    float C1[8];
#pragma unroll
    for (int e = 0; e < 8; e++) {
      float pe1 = (e >= 1) ? hx + hp[e - 1] : hx;
      float tv1 = (e >= 1) ? tx + tp[e - 1] : tx;
      bool tl = tv1 > 0.0f;
      float sel = tl ? tv1 : pe1;
      C1[e] = (tl ? T : 0.0f) + __log2f(sel);  // log2(0) = -inf (empty prefix)
    }

    // w[q] = exp2(S[q] + C[q-1]) + floor ; delta = ln(w)
    float wo[8];
#pragma unroll
    for (int e = 0; e < 8; e++)
      wo[e] = __builtin_amdgcn_exp2f(S[e] + C1[e]) + floorc[e];
    float4* w4 = (float4*)(wb + (size_t)i * J_);
    w4[l * 2]     = make_float4(wo[0], wo[1], wo[2], wo[3]);
    w4[l * 2 + 1] = make_float4(wo[4], wo[5], wo[6], wo[7]);
    float4* d4o = (float4*)(db + (size_t)i * J_);
    d4o[l * 2]     = make_float4(__logf(wo[0]), __logf(wo[1]),
                                 __logf(wo[2]), __logf(wo[3]));
    d4o[l * 2 + 1] = make_float4(__logf(wo[4]), __logf(wo[5]),
                                 __logf(wo[6]), __logf(wo[7]));

    // alpha_{i+1}[p] = V[p-1] + C[p-2] = V[p-1] + C1[p-1]; masked p >= i+1
    if (i < I_ - 1) {
      float prevV7  = dppf<0x138, 0xf, 0xf, false>(NEGINF, V[7]);
      float prevC17 = dppf<0x138, 0xf, 0xf, false>(NEGINF, C1[7]);
#pragma unroll
      for (int e = 0; e < 8; e++) {
        float vp = (e >= 1) ? V[e - 1]  : prevV7;
        float c2 = (e >= 1) ? C1[e - 1] : prevC17;
        Am[e] = ((p0 + e) >= i + 1) ? (vp + c2) : NEGINF;
      }
    }
    Sq0 = Sn0; Sq1 = Sn1; Vq0 = Vn0; Vq1 = Vn1;
  }
}

// ============ Kernel C: expanded[b,j,d] = sum_i w * text ===================
__global__ __launch_bounds__(256) void kernelC(
    const float* __restrict__ wrow, const float* __restrict__ text,
    float* __restrict__ expanded) {
  int bj = blockIdx.x;
  int b = bj >> 9, j = bj & (J_ - 1);
  int d = threadIdx.x;
  __shared__ float w_s[I_];
  if (d < I_) w_s[d] = wrow[(size_t)(b * I_ + d) * J_ + j];
  __syncthreads();
  float acc = 0.0f;
  #pragma unroll 8
  for (int i = 0; i < I_; i++)
    acc += w_s[i] * text[(size_t)(b * I_ + i) * D_ + d];
  expanded[(size_t)(b * J_ + j) * D_ + d] = acc;
}

extern "C" void kernel_launch(void* const* d_in, const int* in_sizes, int n_in,
                              void* d_out, int out_size, void* d_ws, size_t ws_size,
                              hipStream_t stream) {
  (void)in_sizes; (void)n_in; (void)out_size; (void)ws_size;
  const float* text = (const float*)d_in[0];
  const float* mel  = (const float*)d_in[1];
  const unsigned char* tmask = (const unsigned char*)d_in[2];
  const unsigned char* mmask = (const unsigned char*)d_in[3];
  const float* tratio = (const float*)d_in[4];

  float* out = (float*)d_out;
  float* delta = out;                                  // B*I*J
  float* expanded = out + (size_t)B_ * I_ * J_;        // B*J*D
  float* val2  = (float*)d_ws;                         // B*I*J (log2 domain)
  float* sgeq2 = val2 + (size_t)B_ * I_ * J_;          // B*I*J (log2 domain)
  float* wrow  = sgeq2 + (size_t)B_ * I_ * J_;         // B*I*J

  kernelA<<<B_ * I_, 512, 0, stream>>>(text, mel, tmask, mmask, tratio, val2, sgeq2);
  kernelB<<<B_, 64, 0, stream>>>(val2, sgeq2, mmask, wrow, delta);
  kernelC<<<B_ * J_, 256, 0, stream>>>(wrow, text, expanded);
}

// Round 10
// 86.973 us; speedup vs baseline: 1.0738x; 1.0285x over previous
//
#include <hip/hip_runtime.h>
#include <hip/hip_bf16.h>
#include <math.h>

// MoBoAligner forward — closed-form O(B*I*J) reformulation.
//
//   val[b,i,j]   = soft_ok ? (dot/256 - log(-log(u)))/temp : -1000
//   S_geq[b,i,k] = LSE_{j>=k} val[b,i,j]                (reverse cum-LSE)
//   g_i[p] = alpha_i[p] - S_geq[i][p+1]  (-inf if p==J-1 or !mel_mask[p])
//   C_i    = prefix cumLSE of g_i
//   alpha_{i+1}[j] = val[i][j-1] + C_i[j-2]    (masked j >= i+1)
//   w[i][q]  = exp(S_geq[i][q] + C_i[q-1]) + (J-q)*e^-10   ( = exp(delta) )
//   delta = log(w);  expanded[b,j,d] = sum_i w * text  (kernelC)
//
// kernelB: segmented 2-scale scan (r9, exact — see scale analysis below) +
// 8-deep register software pipeline: buffer k holds row i+k; reloaded with
// row i+8+k right after consumption -> ~7 bodies of latency slack. This
// targets the r4/r9 observation that per-iter time (~2100 cy) was constant
// regardless of compute: cross-XCD load latency dominated at 1-deep prefetch.
//
// Scale analysis (exact): true alpha <= 0, S_geq non-increasing and bimodal
// {normal >= -35, collapsed ~ -1443}. gm = alpha - S[p+1] is bimodal: head
// (<= ~35) or spike (~alpha+1443); collapsed-S positions form a SUFFIX.
//   head prefix: log2(plain prefix-sum of 2^gm)            [exact]
//   tail prefix: T + log2(prefix-sum of 2^(gm-T)), T=max   [exact to ulp]
// Mid-scale gm in (60,500): floor-dominated dead zone, clamped to 2^60.

#define B_ 4
#define I_ 64
#define J_ 512
#define D_ 256

#define NEGINF (-INFINITY)
#define LOG2E 1.4426950408889634f
#define SPIKE_THR 500.0f   // head gm <= ~35; spikes ~ +1443 (log2 units)
#define MIDCLAMP 60.0f     // overflow guard for dead-zone mid-scale gm

// ---------------- Threefry-2x32-20, key = (0, 42) --------------------------
__device__ __forceinline__ void tf2x32(unsigned int x0, unsigned int x1,
                                       unsigned int& y0, unsigned int& y1) {
  const unsigned int k0 = 0u, k1 = 42u;
  const unsigned int k2 = k0 ^ k1 ^ 0x1BD11BDAu;
  x0 += k0; x1 += k1;
#define TFR(r) { x0 += x1; x1 = (x1 << r) | (x1 >> (32 - r)); x1 ^= x0; }
  TFR(13) TFR(15) TFR(26) TFR(6)   x0 += k1; x1 += k2 + 1u;
  TFR(17) TFR(29) TFR(16) TFR(24)  x0 += k2; x1 += k0 + 2u;
  TFR(13) TFR(15) TFR(26) TFR(6)   x0 += k0; x1 += k1 + 3u;
  TFR(17) TFR(29) TFR(16) TFR(24)  x0 += k1; x1 += k2 + 4u;
  TFR(13) TFR(15) TFR(26) TFR(6)   x0 += k2; x1 += k0 + 5u;
#undef TFR
  y0 = x0; y1 = x1;
}

__device__ __forceinline__ unsigned int rand_bits(unsigned int n) {
  unsigned int y0, y1;
  tf2x32(0u, n, y0, y1);
  return y0 ^ y1;
}

// log(-log(u)) with u = jax.random.uniform(key(42), ..., 1e-20, 1.0)[n]
__device__ __forceinline__ float gumbel_term(unsigned int n) {
  unsigned int bits = rand_bits(n);
  float f = __uint_as_float((bits >> 9) | 0x3f800000u) - 1.0f;  // [0,1)
  float u = fmaxf(f + 1e-20f, 1e-20f);
  return logf(-logf(u));
}

// ---------------- streaming logsumexp pairs (kernelA, natural log) ---------
struct MS { float m; float s; };

__device__ __forceinline__ MS ms_comb(MS a, MS b) {
  if (b.m == NEGINF) return a;
  if (a.m == NEGINF) return b;
  MS r;
  if (a.m >= b.m) { r.m = a.m; r.s = a.s + b.s * __expf(b.m - a.m); }
  else            { r.m = b.m; r.s = b.s + a.s * __expf(a.m - b.m); }
  return r;
}
__device__ __forceinline__ MS ms_add(MS a, float x) {
  if (x == NEGINF) return a;
  if (a.m == NEGINF) { MS r; r.m = x; r.s = 1.0f; return r; }
  MS r;
  if (a.m >= x) { r.m = a.m; r.s = a.s + __expf(x - a.m); }
  else          { r.m = x;   r.s = 1.0f + a.s * __expf(a.m - x); }
  return r;
}
__device__ __forceinline__ float ms_val(MS a) {
  if (a.m == NEGINF) return NEGINF;
  return a.m + __logf(a.s);
}

__device__ __forceinline__ MS wave_incl_scan(MS v, int lane) {
  #pragma unroll
  for (int off = 1; off < 64; off <<= 1) {
    float mo = __shfl_up(v.m, off, 64);
    float so = __shfl_up(v.s, off, 64);
    if (lane >= off) { MS o; o.m = mo; o.s = so; v = ms_comb(o, v); }
  }
  return v;
}

// ---------------- DPP helpers (kernelB) ------------------------------------
template<int CTRL, int RM, int BM, bool BC>
__device__ __forceinline__ float dppf(float oldv, float src) {
  return __int_as_float(__builtin_amdgcn_update_dpp(
      __float_as_int(oldv), __float_as_int(src), CTRL, RM, BM, BC));
}

// inclusive float add-scan over 64 lanes (invalid sources contribute 0)
__device__ __forceinline__ float wave_incl_add_f(float x) {
  x += dppf<0x111, 0xf, 0xf, false>(0.0f, x);  // row_shr:1
  x += dppf<0x112, 0xf, 0xf, false>(0.0f, x);  // row_shr:2
  x += dppf<0x114, 0xf, 0xf, false>(0.0f, x);  // row_shr:4
  x += dppf<0x118, 0xf, 0xf, false>(0.0f, x);  // row_shr:8
  x += dppf<0x142, 0xa, 0xf, false>(0.0f, x);  // row_bcast:15 -> rows 1,3
  x += dppf<0x143, 0xc, 0xf, false>(0.0f, x);  // row_bcast:31 -> rows 2,3
  return x;
}
// inclusive float max-scan over 64 lanes (invalid sources give -inf: no-op)
__device__ __forceinline__ float wave_incl_max_f(float x) {
  x = fmaxf(x, dppf<0x111, 0xf, 0xf, false>(NEGINF, x));
  x = fmaxf(x, dppf<0x112, 0xf, 0xf, false>(NEGINF, x));
  x = fmaxf(x, dppf<0x114, 0xf, 0xf, false>(NEGINF, x));
  x = fmaxf(x, dppf<0x118, 0xf, 0xf, false>(NEGINF, x));
  x = fmaxf(x, dppf<0x142, 0xa, 0xf, false>(NEGINF, x));
  x = fmaxf(x, dppf<0x143, 0xc, 0xf, false>(NEGINF, x));
  return x;
}

// ---------------- mask helpers (bool-bytes vs int32 auto-detect) -----------
__device__ __forceinline__ bool mask_is_byte(const unsigned char* p) {
  const unsigned int* w = (const unsigned int*)p;
  unsigned int orbits = 0;
  #pragma unroll
  for (int k = 0; k < 16; k++) orbits |= w[k];
  return (orbits & 0xFFFFFF00u) != 0u;  // any high byte set -> byte layout
}
__device__ __forceinline__ int mask_get(const unsigned char* p, int idx, bool isbyte) {
  return isbyte ? (p[idx] != 0) : (((const int*)p)[idx] != 0);
}

// ============ Kernel A: val + S_geq per (b,i) row (stored in log2 domain) ==
__global__ __launch_bounds__(512) void kernelA(
    const float* __restrict__ text, const float* __restrict__ mel,
    const unsigned char* __restrict__ tmask, const unsigned char* __restrict__ mmask,
    const float* __restrict__ tratio,
    float* __restrict__ val2, float* __restrict__ sgeq2) {
  int bi = blockIdx.x;
  int b = bi >> 6, i = bi & 63;
  int tid = threadIdx.x;

  __shared__ float t_s[D_];
  __shared__ float v_s[J_];
  __shared__ int sh_ilen, sh_tok, sh_mbyte;

  if (tid == 0) {
    bool tbyte = mask_is_byte(tmask);
    int ilen = 0;
    for (int k = 0; k < I_; k++) ilen += mask_get(tmask, b * I_ + k, tbyte);
    sh_ilen = ilen;
    sh_tok = mask_get(tmask, b * I_ + i, tbyte);
    sh_mbyte = mask_is_byte(mmask) ? 1 : 0;
  }
  if (tid < D_) t_s[tid] = text[(size_t)(b * I_ + i) * D_ + tid];
  __syncthreads();

  int j = tid;  // 512 threads = one j each
  const float4* m4 = (const float4*)(mel + (size_t)(b * J_ + j) * D_);
  const float4* t4 = (const float4*)t_s;
  float4 acc; acc.x = acc.y = acc.z = acc.w = 0.0f;
  #pragma unroll 8
  for (int d4 = 0; d4 < D_ / 4; ++d4) {
    float4 a = m4[d4]; float4 t = t4[d4];
    acc.x += a.x * t.x; acc.y += a.y * t.y;
    acc.z += a.z * t.z; acc.w += a.w * t.w;
  }
  float dot = (acc.x + acc.y) + (acc.z + acc.w);

  float temp = 0.1f + 0.9f * tratio[0];
  float gum = gumbel_term((unsigned)((b * I_ + i) * J_ + j));
  float e = (dot * (1.0f / 256.0f) - gum) / temp;
  int mok = mask_get(mmask, b * J_ + j, sh_mbyte != 0);
  int hi = J_ - sh_ilen + i + 1;
  bool ok = (j >= i + 1) && (j <= hi) && mok && sh_tok;
  float v = ok ? e : -1000.0f;
  v_s[j] = v;                                   // natural log domain (internal)
  val2[(size_t)bi * J_ + j] = v * LOG2E;        // log2 domain for kernelB
  __syncthreads();

  // reverse cumulative LSE by wave 0: p = reversed index, lane l owns p=l*8+e
  if (tid < 64) {
    int l = tid;
    float xs[8];
    MS tot; tot.m = NEGINF; tot.s = 0.0f;
    #pragma unroll
    for (int e = 0; e < 8; e++) {
      int p = l * 8 + e;
      xs[e] = v_s[J_ - 1 - p];
      tot = ms_add(tot, xs[e]);
    }
    MS inc = wave_incl_scan(tot, l);
    MS ex; ex.m = __shfl_up(inc.m, 1, 64); ex.s = __shfl_up(inc.s, 1, 64);
    if (l == 0) { ex.m = NEGINF; ex.s = 0.0f; }
    MS run = ex;
    #pragma unroll
    for (int e = 0; e < 8; e++) {
      int p = l * 8 + e;
      run = ms_add(run, xs[e]);
      sgeq2[(size_t)bi * J_ + (J_ - 1 - p)] = ms_val(run) * LOG2E;
    }
  }
}

// ---------------- kernelB body: one DP row (math identical to r9) ----------
__device__ __forceinline__ void dp_body(
    int i, int p0, float4 Sa, float4 Sb, float4 Va, float4 Vb,
    float (&Am)[8], const float (&gokb)[8], const float (&floorc)[8],
    float* __restrict__ wb, float* __restrict__ db, int l) {
  float S[8] = {Sa.x, Sa.y, Sa.z, Sa.w, Sb.x, Sb.y, Sb.z, Sb.w};
  float V[8] = {Va.x, Va.y, Va.z, Va.w, Vb.x, Vb.y, Vb.z, Vb.w};

  // g[p] = alpha[p] - S[p+1] + mask; e=7 needs next lane's S[0]
  float nextS0 = dppf<0x130, 0xf, 0xf, false>(0.0f, S[0]);  // wave_shl:1
  float gm[8];
#pragma unroll
  for (int e = 0; e < 8; e++) {
    float sp1 = (e < 7) ? S[e + 1] : nextS0;
    gm[e] = (Am[e] - sp1) + gokb[e];   // -inf propagates, never NaN
  }

  // T = wave max of gm (only consumed at spike lanes, where it's finite)
  float m01 = fmaxf(gm[0], gm[1]), m23 = fmaxf(gm[2], gm[3]);
  float m45 = fmaxf(gm[4], gm[5]), m67 = fmaxf(gm[6], gm[7]);
  float lmax = fmaxf(fmaxf(m01, m23), fmaxf(m45, m67));
  float msc = wave_incl_max_f(lmax);
  const float T = __int_as_float(
      __builtin_amdgcn_readlane(__float_as_int(msc), 63));

  // two-scale exp terms: head at 2^0 (clamped), tail (spikes) at 2^T
  float h[8], t[8];
#pragma unroll
  for (int e = 0; e < 8; e++) {
    bool spk = gm[e] > SPIKE_THR;
    float arg = spk ? (gm[e] - T) : fminf(gm[e], MIDCLAMP);
    float x = __builtin_amdgcn_exp2f(arg);   // gm=-inf -> 0
    h[e] = spk ? 0.0f : x;
    t[e] = spk ? x : 0.0f;
  }

  // in-lane inclusive prefixes (two independent chains, ILP)
  float hp[8], tp[8];
  hp[0] = h[0]; tp[0] = t[0];
#pragma unroll
  for (int e = 1; e < 8; e++) { hp[e] = hp[e - 1] + h[e]; tp[e] = tp[e - 1] + t[e]; }

  // wave add-scans of lane totals; exclusive via wave_shr:1 (lane0 -> 0)
  float hincl = wave_incl_add_f(hp[7]);
  float tincl = wave_incl_add_f(tp[7]);
  float hx = dppf<0x138, 0xf, 0xf, false>(0.0f, hincl);
  float tx = dppf<0x138, 0xf, 0xf, false>(0.0f, tincl);

  // prefix sums through p-1, then C1[e] = C[p-1] (true log2 value)
  float C1[8];
#pragma unroll
  for (int e = 0; e < 8; e++) {
    float pe1 = (e >= 1) ? hx + hp[e - 1] : hx;
    float tv1 = (e >= 1) ? tx + tp[e - 1] : tx;
    bool tl = tv1 > 0.0f;
    float sel = tl ? tv1 : pe1;
    C1[e] = (tl ? T : 0.0f) + __log2f(sel);  // log2(0) = -inf (empty prefix)
  }

  // w[q] = exp2(S[q] + C[q-1]) + floor ; delta = ln(w)
  float wo[8];
#pragma unroll
  for (int e = 0; e < 8; e++)
    wo[e] = __builtin_amdgcn_exp2f(S[e] + C1[e]) + floorc[e];
  float4* w4 = (float4*)(wb + (size_t)i * J_);
  w4[l * 2]     = make_float4(wo[0], wo[1], wo[2], wo[3]);
  w4[l * 2 + 1] = make_float4(wo[4], wo[5], wo[6], wo[7]);
  float4* d4o = (float4*)(db + (size_t)i * J_);
  d4o[l * 2]     = make_float4(__logf(wo[0]), __logf(wo[1]),
                               __logf(wo[2]), __logf(wo[3]));
  d4o[l * 2 + 1] = make_float4(__logf(wo[4]), __logf(wo[5]),
                               __logf(wo[6]), __logf(wo[7]));

  // alpha_{i+1}[p] = V[p-1] + C[p-2] = V[p-1] + C1[p-1]; masked p >= i+1
  if (i < I_ - 1) {
    float prevV7  = dppf<0x138, 0xf, 0xf, false>(NEGINF, V[7]);
    float prevC17 = dppf<0x138, 0xf, 0xf, false>(NEGINF, C1[7]);
#pragma unroll
    for (int e = 0; e < 8; e++) {
      float vp = (e >= 1) ? V[e - 1]  : prevV7;
      float c2 = (e >= 1) ? C1[e - 1] : prevC17;
      Am[e] = ((p0 + e) >= i + 1) ? (vp + c2) : NEGINF;
    }
  }
}

// ============ Kernel B: DP over i — 8-deep register pipeline ===============
// 1 wave/batch, lane l owns p = l*8+e. Buffer k holds row i+k; after body k
// consumes it, it is reloaded with row i+8+k -> ~7 bodies of latency slack.
__global__ __launch_bounds__(64) void kernelB(
    const float* __restrict__ val2, const float* __restrict__ sgeq2,
    const unsigned char* __restrict__ mmask,
    float* __restrict__ wrow, float* __restrict__ delta) {
  const int b = blockIdx.x;
  const int l = threadIdx.x;
  const int p0 = l << 3;

  const bool mbyte = mask_is_byte(mmask);
  float gokb[8], floorc[8], Am[8];
#pragma unroll
  for (int e = 0; e < 8; e++) {
    int p = p0 + e;
    bool ok = (p <= J_ - 2) && (mask_get(mmask, b * J_ + p, mbyte) != 0);
    gokb[e] = ok ? 0.0f : NEGINF;                           // additive mask
    floorc[e] = (float)(J_ - p) * 4.5399929762484854e-05f;  // (J-q)*e^-10
    Am[e] = (p == 0) ? 0.0f : NEGINF;
  }

  const float4* sb4 = (const float4*)(sgeq2 + (size_t)b * I_ * J_);
  const float4* vb4 = (const float4*)(val2  + (size_t)b * I_ * J_);
  float* wb = wrow  + (size_t)b * I_ * J_;
  float* db = delta + (size_t)b * I_ * J_;

  float4 Sa0, Sb0, Va0, Vb0, Sa1, Sb1, Va1, Vb1;
  float4 Sa2, Sb2, Va2, Vb2, Sa3, Sb3, Va3, Vb3;
  float4 Sa4, Sb4, Va4, Vb4, Sa5, Sb5, Va5, Vb5;
  float4 Sa6, Sb6, Va6, Vb6, Sa7, Sb7, Va7, Vb7;

#define LOADROW(k, row) { const int _ro = (row) * (J_ / 4) + (l << 1); \
    Sa##k = sb4[_ro]; Sb##k = sb4[_ro + 1]; \
    Va##k = vb4[_ro]; Vb##k = vb4[_ro + 1]; }

  // prologue: rows 0..7 into buffers 0..7 (32 loads in flight)
  LOADROW(0, 0) LOADROW(1, 1) LOADROW(2, 2) LOADROW(3, 3)
  LOADROW(4, 4) LOADROW(5, 5) LOADROW(6, 6) LOADROW(7, 7)

#define STEP(k) { \
    const int i = ii + k; \
    dp_body(i, p0, Sa##k, Sb##k, Va##k, Vb##k, Am, gokb, floorc, wb, db, l); \
    const int nr = (i + 8 < I_) ? i + 8 : I_ - 1; \
    LOADROW(k, nr) }

  for (int ii = 0; ii < I_; ii += 8) {
    STEP(0) STEP(1) STEP(2) STEP(3) STEP(4) STEP(5) STEP(6) STEP(7)
  }
#undef STEP
#undef LOADROW
}

// ============ Kernel C: expanded[b,j,d] = sum_i w * text ===================
__global__ __launch_bounds__(256) void kernelC(
    const float* __restrict__ wrow, const float* __restrict__ text,
    float* __restrict__ expanded) {
  int bj = blockIdx.x;
  int b = bj >> 9, j = bj & (J_ - 1);
  int d = threadIdx.x;
  __shared__ float w_s[I_];
  if (d < I_) w_s[d] = wrow[(size_t)(b * I_ + d) * J_ + j];
  __syncthreads();
  float acc = 0.0f;
  #pragma unroll 8
  for (int i = 0; i < I_; i++)
    acc += w_s[i] * text[(size_t)(b * I_ + i) * D_ + d];
  expanded[(size_t)(b * J_ + j) * D_ + d] = acc;
}

extern "C" void kernel_launch(void* const* d_in, const int* in_sizes, int n_in,
                              void* d_out, int out_size, void* d_ws, size_t ws_size,
                              hipStream_t stream) {
  (void)in_sizes; (void)n_in; (void)out_size; (void)ws_size;
  const float* text = (const float*)d_in[0];
  const float* mel  = (const float*)d_in[1];
  const unsigned char* tmask = (const unsigned char*)d_in[2];
  const unsigned char* mmask = (const unsigned char*)d_in[3];
  const float* tratio = (const float*)d_in[4];

  float* out = (float*)d_out;
  float* delta = out;                                  // B*I*J
  float* expanded = out + (size_t)B_ * I_ * J_;        // B*J*D
  float* val2  = (float*)d_ws;                         // B*I*J (log2 domain)
  float* sgeq2 = val2 + (size_t)B_ * I_ * J_;          // B*I*J (log2 domain)
  float* wrow  = sgeq2 + (size_t)B_ * I_ * J_;         // B*I*J

  kernelA<<<B_ * I_, 512, 0, stream>>>(text, mel, tmask, mmask, tratio, val2, sgeq2);
  kernelB<<<B_, 64, 0, stream>>>(val2, sgeq2, mmask, wrow, delta);
  kernelC<<<B_ * J_, 256, 0, stream>>>(wrow, text, expanded);
}

// Round 11
// 70.232 us; speedup vs baseline: 1.3297x; 1.2384x over previous
//
#include <hip/hip_runtime.h>
#include <hip/hip_bf16.h>
#include <math.h>

// MoBoAligner forward — closed-form O(B*I*J) reformulation.
//
//   val[b,i,j]   = soft_ok ? (dot/256 - log(-log(u)))/temp : -1000
//   S_geq[b,i,k] = LSE_{j>=k} val[b,i,j]                (reverse cum-LSE)
//   g_i[p] = alpha_i[p] - S_geq[i][p+1]  (-inf if p==J-1 or !mel_mask[p])
//   C_i    = prefix cumLSE of g_i
//   alpha_{i+1}[j] = val[i][j-1] + C_i[j-2]    (masked j >= i+1)
//   w[i][q]  = exp(S_geq[i][q] + C_i[q-1]) + (J-q)*e^-10   ( = exp(delta) )
//   delta = log(w)  and  expanded = sum_i w * text   (fused kernelCD)
//
// kernelB (issue-bound at low DVFS clock -> minimize instructions):
// r9's segmented 2-scale scan, 1-deep prefetch, with (a) delta moved out,
// (b) per-row wave max-scan replaced by fixed tail scale Tfix:
//   spikes gm = alpha - S_collapsed <= 1442.7/temp  (alpha <= 0, S_coll >=
//   -1000/temp nats), so Tfix = 1442.7/temp + 40 gives gm-Tfix <= -40:
//   no overflow; flushed terms need alpha < -86 -> w ~ 2^alpha, 70+ bits
//   below the e^-10 floor -> invisible. Rows w/o spikes never use Tfix.
//
// Scale analysis (exact): true alpha <= 0, S_geq non-increasing and bimodal
// {normal >= ~-50, collapsed ~ -1443/temp}. gm is bimodal: head (<= ~50) or
// spike; collapsed-S positions form a SUFFIX. Prefix-LSE therefore splits:
//   head prefix: log2(plain prefix-sum of 2^gm)              [exact]
//   tail prefix: Tfix + log2(prefix-sum of 2^(gm-Tfix))      [exact to ulp]
// Mid-scale gm in (60,500): floor-dominated dead zone, clamped to 2^60.

#define B_ 4
#define I_ 64
#define J_ 512
#define D_ 256

#define NEGINF (-INFINITY)
#define LOG2E 1.4426950408889634f
#define SPIKE_THR 500.0f   // head gm <= ~50; spikes ~ +1443/temp (log2 units)
#define MIDCLAMP 60.0f     // overflow guard for dead-zone mid-scale gm

// ---------------- Threefry-2x32-20, key = (0, 42) --------------------------
__device__ __forceinline__ void tf2x32(unsigned int x0, unsigned int x1,
                                       unsigned int& y0, unsigned int& y1) {
  const unsigned int k0 = 0u, k1 = 42u;
  const unsigned int k2 = k0 ^ k1 ^ 0x1BD11BDAu;
  x0 += k0; x1 += k1;
#define TFR(r) { x0 += x1; x1 = (x1 << r) | (x1 >> (32 - r)); x1 ^= x0; }
  TFR(13) TFR(15) TFR(26) TFR(6)   x0 += k1; x1 += k2 + 1u;
  TFR(17) TFR(29) TFR(16) TFR(24)  x0 += k2; x1 += k0 + 2u;
  TFR(13) TFR(15) TFR(26) TFR(6)   x0 += k0; x1 += k1 + 3u;
  TFR(17) TFR(29) TFR(16) TFR(24)  x0 += k1; x1 += k2 + 4u;
  TFR(13) TFR(15) TFR(26) TFR(6)   x0 += k2; x1 += k0 + 5u;
#undef TFR
  y0 = x0; y1 = x1;
}

__device__ __forceinline__ unsigned int rand_bits(unsigned int n) {
  unsigned int y0, y1;
  tf2x32(0u, n, y0, y1);
  return y0 ^ y1;
}

// log(-log(u)) with u = jax.random.uniform(key(42), ..., 1e-20, 1.0)[n]
__device__ __forceinline__ float gumbel_term(unsigned int n) {
  unsigned int bits = rand_bits(n);
  float f = __uint_as_float((bits >> 9) | 0x3f800000u) - 1.0f;  // [0,1)
  float u = fmaxf(f + 1e-20f, 1e-20f);
  return logf(-logf(u));
}

// ---------------- streaming logsumexp pairs (kernelA, natural log) ---------
struct MS { float m; float s; };

__device__ __forceinline__ MS ms_comb(MS a, MS b) {
  if (b.m == NEGINF) return a;
  if (a.m == NEGINF) return b;
  MS r;
  if (a.m >= b.m) { r.m = a.m; r.s = a.s + b.s * __expf(b.m - a.m); }
  else            { r.m = b.m; r.s = b.s + a.s * __expf(a.m - b.m); }
  return r;
}
__device__ __forceinline__ MS ms_add(MS a, float x) {
  if (x == NEGINF) return a;
  if (a.m == NEGINF) { MS r; r.m = x; r.s = 1.0f; return r; }
  MS r;
  if (a.m >= x) { r.m = a.m; r.s = a.s + __expf(x - a.m); }
  else          { r.m = x;   r.s = 1.0f + a.s * __expf(a.m - x); }
  return r;
}
__device__ __forceinline__ float ms_val(MS a) {
  if (a.m == NEGINF) return NEGINF;
  return a.m + __logf(a.s);
}

__device__ __forceinline__ MS wave_incl_scan(MS v, int lane) {
  #pragma unroll
  for (int off = 1; off < 64; off <<= 1) {
    float mo = __shfl_up(v.m, off, 64);
    float so = __shfl_up(v.s, off, 64);
    if (lane >= off) { MS o; o.m = mo; o.s = so; v = ms_comb(o, v); }
  }
  return v;
}

// ---------------- DPP helpers (kernelB) ------------------------------------
template<int CTRL, int RM, int BM, bool BC>
__device__ __forceinline__ float dppf(float oldv, float src) {
  return __int_as_float(__builtin_amdgcn_update_dpp(
      __float_as_int(oldv), __float_as_int(src), CTRL, RM, BM, BC));
}

// inclusive float add-scan over 64 lanes (invalid sources contribute 0)
__device__ __forceinline__ float wave_incl_add_f(float x) {
  x += dppf<0x111, 0xf, 0xf, false>(0.0f, x);  // row_shr:1
  x += dppf<0x112, 0xf, 0xf, false>(0.0f, x);  // row_shr:2
  x += dppf<0x114, 0xf, 0xf, false>(0.0f, x);  // row_shr:4
  x += dppf<0x118, 0xf, 0xf, false>(0.0f, x);  // row_shr:8
  x += dppf<0x142, 0xa, 0xf, false>(0.0f, x);  // row_bcast:15 -> rows 1,3
  x += dppf<0x143, 0xc, 0xf, false>(0.0f, x);  // row_bcast:31 -> rows 2,3
  return x;
}

// ---------------- mask helpers (bool-bytes vs int32 auto-detect) -----------
__device__ __forceinline__ bool mask_is_byte(const unsigned char* p) {
  const unsigned int* w = (const unsigned int*)p;
  unsigned int orbits = 0;
  #pragma unroll
  for (int k = 0; k < 16; k++) orbits |= w[k];
  return (orbits & 0xFFFFFF00u) != 0u;  // any high byte set -> byte layout
}
__device__ __forceinline__ int mask_get(const unsigned char* p, int idx, bool isbyte) {
  return isbyte ? (p[idx] != 0) : (((const int*)p)[idx] != 0);
}

// ============ Kernel A: val + S_geq per (b,i) row (stored in log2 domain) ==
__global__ __launch_bounds__(512) void kernelA(
    const float* __restrict__ text, const float* __restrict__ mel,
    const unsigned char* __restrict__ tmask, const unsigned char* __restrict__ mmask,
    const float* __restrict__ tratio,
    float* __restrict__ val2, float* __restrict__ sgeq2) {
  int bi = blockIdx.x;
  int b = bi >> 6, i = bi & 63;
  int tid = threadIdx.x;

  __shared__ float t_s[D_];
  __shared__ float v_s[J_];
  __shared__ int sh_ilen, sh_tok, sh_mbyte;

  if (tid == 0) {
    bool tbyte = mask_is_byte(tmask);
    int ilen = 0;
    for (int k = 0; k < I_; k++) ilen += mask_get(tmask, b * I_ + k, tbyte);
    sh_ilen = ilen;
    sh_tok = mask_get(tmask, b * I_ + i, tbyte);
    sh_mbyte = mask_is_byte(mmask) ? 1 : 0;
  }
  if (tid < D_) t_s[tid] = text[(size_t)(b * I_ + i) * D_ + tid];
  __syncthreads();

  int j = tid;  // 512 threads = one j each
  const float4* m4 = (const float4*)(mel + (size_t)(b * J_ + j) * D_);
  const float4* t4 = (const float4*)t_s;
  float4 acc; acc.x = acc.y = acc.z = acc.w = 0.0f;
  #pragma unroll 8
  for (int d4 = 0; d4 < D_ / 4; ++d4) {
    float4 a = m4[d4]; float4 t = t4[d4];
    acc.x += a.x * t.x; acc.y += a.y * t.y;
    acc.z += a.z * t.z; acc.w += a.w * t.w;
  }
  float dot = (acc.x + acc.y) + (acc.z + acc.w);

  float temp = 0.1f + 0.9f * tratio[0];
  float gum = gumbel_term((unsigned)((b * I_ + i) * J_ + j));
  float e = (dot * (1.0f / 256.0f) - gum) / temp;
  int mok = mask_get(mmask, b * J_ + j, sh_mbyte != 0);
  int hi = J_ - sh_ilen + i + 1;
  bool ok = (j >= i + 1) && (j <= hi) && mok && sh_tok;
  float v = ok ? e : -1000.0f;
  v_s[j] = v;                                   // natural log domain (internal)
  val2[(size_t)bi * J_ + j] = v * LOG2E;        // log2 domain for kernelB
  __syncthreads();

  // reverse cumulative LSE by wave 0: p = reversed index, lane l owns p=l*8+e
  if (tid < 64) {
    int l = tid;
    float xs[8];
    MS tot; tot.m = NEGINF; tot.s = 0.0f;
    #pragma unroll
    for (int e = 0; e < 8; e++) {
      int p = l * 8 + e;
      xs[e] = v_s[J_ - 1 - p];
      tot = ms_add(tot, xs[e]);
    }
    MS inc = wave_incl_scan(tot, l);
    MS ex; ex.m = __shfl_up(inc.m, 1, 64); ex.s = __shfl_up(inc.s, 1, 64);
    if (l == 0) { ex.m = NEGINF; ex.s = 0.0f; }
    MS run = ex;
    #pragma unroll
    for (int e = 0; e < 8; e++) {
      int p = l * 8 + e;
      run = ms_add(run, xs[e]);
      sgeq2[(size_t)bi * J_ + (J_ - 1 - p)] = ms_val(run) * LOG2E;
    }
  }
}

// ============ Kernel B: DP over i — 1 wave/batch, fixed tail scale =========
// lane l owns p = l*8 + e. No LDS, no barriers. All values log2 domain.
// r9 structure (passed), minus delta output, minus per-row max-scan.
__global__ __launch_bounds__(64) void kernelB(
    const float* __restrict__ val2, const float* __restrict__ sgeq2,
    const unsigned char* __restrict__ mmask, const float* __restrict__ tratio,
    float* __restrict__ wrow) {
  const int b = blockIdx.x;
  const int l = threadIdx.x;
  const int p0 = l << 3;

  const float temp = 0.1f + 0.9f * tratio[0];
  const float Tfix = 1442.695f / temp + 40.0f;  // >= max spike + 40

  const bool mbyte = mask_is_byte(mmask);
  float gokb[8], floorc[8], Am[8];
#pragma unroll
  for (int e = 0; e < 8; e++) {
    int p = p0 + e;
    bool ok = (p <= J_ - 2) && (mask_get(mmask, b * J_ + p, mbyte) != 0);
    gokb[e] = ok ? 0.0f : NEGINF;                           // additive mask
    floorc[e] = (float)(J_ - p) * 4.5399929762484854e-05f;  // (J-q)*e^-10
    Am[e] = (p == 0) ? 0.0f : NEGINF;
  }

  const float4* sb4 = (const float4*)(sgeq2 + (size_t)b * I_ * J_);
  const float4* vb4 = (const float4*)(val2  + (size_t)b * I_ * J_);
  float* wb = wrow + (size_t)b * I_ * J_;

  float4 Sq0 = sb4[l * 2], Sq1 = sb4[l * 2 + 1];
  float4 Vq0 = vb4[l * 2], Vq1 = vb4[l * 2 + 1];

  for (int i = 0; i < I_; i++) {
    // prefetch next row (clamped; redundant reload on last iter harmless)
    const int rn = (i + 1 < I_) ? i + 1 : i;
    const int ro = rn * (J_ / 4);
    float4 Sn0 = sb4[ro + l * 2], Sn1 = sb4[ro + l * 2 + 1];
    float4 Vn0 = vb4[ro + l * 2], Vn1 = vb4[ro + l * 2 + 1];

    float S[8] = {Sq0.x, Sq0.y, Sq0.z, Sq0.w, Sq1.x, Sq1.y, Sq1.z, Sq1.w};
    float V[8] = {Vq0.x, Vq0.y, Vq0.z, Vq0.w, Vq1.x, Vq1.y, Vq1.z, Vq1.w};

    // g[p] = alpha[p] - S[p+1] + mask; e=7 needs next lane's S[0]
    float nextS0 = dppf<0x130, 0xf, 0xf, false>(0.0f, S[0]);  // wave_shl:1
    float gm[8];
#pragma unroll
    for (int e = 0; e < 8; e++) {
      float sp1 = (e < 7) ? S[e + 1] : nextS0;
      gm[e] = (Am[e] - sp1) + gokb[e];   // -inf propagates, never NaN
    }

    // two-scale exp terms: head at 2^0 (clamped), tail (spikes) at 2^Tfix
    float h[8], t[8];
#pragma unroll
    for (int e = 0; e < 8; e++) {
      bool spk = gm[e] > SPIKE_THR;
      float arg = spk ? (gm[e] - Tfix) : fminf(gm[e], MIDCLAMP);
      float x = __builtin_amdgcn_exp2f(arg);   // gm=-inf -> 0
      h[e] = spk ? 0.0f : x;
      t[e] = spk ? x : 0.0f;
    }

    // in-lane inclusive prefixes (two independent chains, ILP)
    float hp[8], tp[8];
    hp[0] = h[0]; tp[0] = t[0];
#pragma unroll
    for (int e = 1; e < 8; e++) { hp[e] = hp[e - 1] + h[e]; tp[e] = tp[e - 1] + t[e]; }

    // wave add-scans of lane totals; exclusive via wave_shr:1 (lane0 -> 0)
    float hincl = wave_incl_add_f(hp[7]);
    float tincl = wave_incl_add_f(tp[7]);
    float hx = dppf<0x138, 0xf, 0xf, false>(0.0f, hincl);
    float tx = dppf<0x138, 0xf, 0xf, false>(0.0f, tincl);

    // prefix sums through p-1, then C1[e] = C[p-1] (true log2 value)
    float C1[8];
#pragma unroll
    for (int e = 0; e < 8; e++) {
      float pe1 = (e >= 1) ? hx + hp[e - 1] : hx;
      float tv1 = (e >= 1) ? tx + tp[e - 1] : tx;
      bool tl = tv1 > 0.0f;
      float sel = tl ? tv1 : pe1;
      C1[e] = (tl ? Tfix : 0.0f) + __log2f(sel);  // log2(0) = -inf (empty)
    }

    // w[q] = exp2(S[q] + C[q-1]) + floor   (delta = log(w) done in kernelCD)
    float wo[8];
#pragma unroll
    for (int e = 0; e < 8; e++)
      wo[e] = __builtin_amdgcn_exp2f(S[e] + C1[e]) + floorc[e];
    float4* w4 = (float4*)(wb + (size_t)i * J_);
    w4[l * 2]     = make_float4(wo[0], wo[1], wo[2], wo[3]);
    w4[l * 2 + 1] = make_float4(wo[4], wo[5], wo[6], wo[7]);

    // alpha_{i+1}[p] = V[p-1] + C[p-2] = V[p-1] + C1[p-1]; masked p >= i+1
    if (i < I_ - 1) {
      float prevV7  = dppf<0x138, 0xf, 0xf, false>(NEGINF, V[7]);
      float prevC17 = dppf<0x138, 0xf, 0xf, false>(NEGINF, C1[7]);
#pragma unroll
      for (int e = 0; e < 8; e++) {
        float vp = (e >= 1) ? V[e - 1]  : prevV7;
        float c2 = (e >= 1) ? C1[e - 1] : prevC17;
        Am[e] = ((p0 + e) >= i + 1) ? (vp + c2) : NEGINF;
      }
    }
    Sq0 = Sn0; Sq1 = Sn1; Vq0 = Vn0; Vq1 = Vn1;
  }
}

// ============ Kernel CD: expanded (blocks < B*J) + delta (rest) ============
__global__ __launch_bounds__(256) void kernelCD(
    const float* __restrict__ wrow, const float* __restrict__ text,
    float* __restrict__ expanded, float* __restrict__ delta) {
  int blk = blockIdx.x;
  if (blk < B_ * J_) {
    int b = blk >> 9, j = blk & (J_ - 1);
    int d = threadIdx.x;
    __shared__ float w_s[I_];
    if (d < I_) w_s[d] = wrow[(size_t)(b * I_ + d) * J_ + j];
    __syncthreads();
    float acc = 0.0f;
    #pragma unroll 8
    for (int i = 0; i < I_; i++)
      acc += w_s[i] * text[(size_t)(b * I_ + i) * D_ + d];
    expanded[(size_t)(b * J_ + j) * D_ + d] = acc;
  } else {
    int n = (blk - B_ * J_) * 256 + threadIdx.x;  // B*I*J / 256 blocks
    delta[n] = __logf(wrow[n]);
  }
}

extern "C" void kernel_launch(void* const* d_in, const int* in_sizes, int n_in,
                              void* d_out, int out_size, void* d_ws, size_t ws_size,
                              hipStream_t stream) {
  (void)in_sizes; (void)n_in; (void)out_size; (void)ws_size;
  const float* text = (const float*)d_in[0];
  const float* mel  = (const float*)d_in[1];
  const unsigned char* tmask = (const unsigned char*)d_in[2];
  const unsigned char* mmask = (const unsigned char*)d_in[3];
  const float* tratio = (const float*)d_in[4];

  float* out = (float*)d_out;
  float* delta = out;                                  // B*I*J
  float* expanded = out + (size_t)B_ * I_ * J_;        // B*J*D
  float* val2  = (float*)d_ws;                         // B*I*J (log2 domain)
  float* sgeq2 = val2 + (size_t)B_ * I_ * J_;          // B*I*J (log2 domain)
  float* wrow  = sgeq2 + (size_t)B_ * I_ * J_;         // B*I*J

  kernelA<<<B_ * I_, 512, 0, stream>>>(text, mel, tmask, mmask, tratio, val2, sgeq2);
  kernelB<<<B_, 64, 0, stream>>>(val2, sgeq2, mmask, tratio, wrow);
  kernelCD<<<B_ * J_ + (B_ * I_ * J_) / 256, 256, 0, stream>>>(
      wrow, text, expanded, delta);
}